// Round 2
// baseline (6867.476 us; speedup 1.0000x reference)
//
#include <hip/hip_runtime.h>
#include <hip/hip_bf16.h>
#include <math.h>

#define EPSBN 1e-5f

// order-preserving float<->uint for atomicMax-based segment max
__device__ __forceinline__ unsigned ford(float f) {
  unsigned u = __float_as_uint(f);
  return (u & 0x80000000u) ? ~u : (u | 0x80000000u);
}
__device__ __forceinline__ float funord(unsigned u) {
  return (u & 0x80000000u) ? __uint_as_float(u & 0x7fffffffu) : __uint_as_float(~u);
}

// ---------------------------------------------------------------------------
// C[M,256] = A[M,256] @ W[256,256], f32, LDS-tiled 64x64, 256 thr, 4x4/thread
// ---------------------------------------------------------------------------
__global__ __launch_bounds__(256) void gemm256(const float* __restrict__ A,
                                               const float* __restrict__ W,
                                               float* __restrict__ C, int M) {
  __shared__ float As[64][20];  // [m][k], row stride 20 floats keeps float4 alignment
  __shared__ float Bs[16][68];  // [k][n], row stride 68 floats (272B, 16B-aligned)
  const int tid = threadIdx.x;
  const int tx = tid & 15, ty = tid >> 4;
  const int bm = blockIdx.x * 64, bn = blockIdx.y * 64;
  float acc[4][4] = {};
  for (int k0 = 0; k0 < 256; k0 += 16) {
    {
      int r = tid >> 2;            // 0..63
      int kc = (tid & 3) * 4;      // 0,4,8,12
      int gr = bm + r;
      float4 v = make_float4(0.f, 0.f, 0.f, 0.f);
      if (gr < M) v = *(const float4*)&A[(size_t)gr * 256 + k0 + kc];
      *(float4*)&As[r][kc] = v;
      int kr = tid >> 4;           // 0..15
      int nc = (tid & 15) * 4;     // 0..60
      float4 w = *(const float4*)&W[(size_t)(k0 + kr) * 256 + bn + nc];
      *(float4*)&Bs[kr][nc] = w;
    }
    __syncthreads();
#pragma unroll
    for (int kk = 0; kk < 16; ++kk) {
      float a0 = As[ty * 4 + 0][kk];
      float a1 = As[ty * 4 + 1][kk];
      float a2 = As[ty * 4 + 2][kk];
      float a3 = As[ty * 4 + 3][kk];
      float4 b = *(float4*)&Bs[kk][tx * 4];
      acc[0][0] += a0 * b.x; acc[0][1] += a0 * b.y; acc[0][2] += a0 * b.z; acc[0][3] += a0 * b.w;
      acc[1][0] += a1 * b.x; acc[1][1] += a1 * b.y; acc[1][2] += a1 * b.z; acc[1][3] += a1 * b.w;
      acc[2][0] += a2 * b.x; acc[2][1] += a2 * b.y; acc[2][2] += a2 * b.z; acc[2][3] += a2 * b.w;
      acc[3][0] += a3 * b.x; acc[3][1] += a3 * b.y; acc[3][2] += a3 * b.z; acc[3][3] += a3 * b.w;
    }
    __syncthreads();
  }
#pragma unroll
  for (int i = 0; i < 4; ++i) {
    int gr = bm + ty * 4 + i;
    if (gr < M) {
      *(float4*)&C[(size_t)gr * 256 + bn + tx * 4] =
          make_float4(acc[i][0], acc[i][1], acc[i][2], acc[i][3]);
    }
  }
}

// ---------------------------------------------------------------------------
// one wave per edge: lane l -> head h=l>>4, channels (l&15)*4 .. +3
// score[e,h] = dot(leaky_relu(xl[s]+xr[d]), att[h]); atomicMax running max/dst
// ---------------------------------------------------------------------------
__global__ __launch_bounds__(256) void edge_score(const float* __restrict__ xl,
                                                  const float* __restrict__ xr,
                                                  const int* __restrict__ ei,
                                                  const float* __restrict__ att,
                                                  float* __restrict__ score,
                                                  unsigned* __restrict__ mord,
                                                  int Etot, int Eorig) {
  int wid = (blockIdx.x << 2) + (threadIdx.x >> 6);
  if (wid >= Etot) return;
  int lane = threadIdx.x & 63;
  int s, d;
  if (wid < Eorig) { s = ei[wid]; d = ei[Eorig + wid]; }
  else { s = wid - Eorig; d = s; }
  float4 a = *(const float4*)&xl[(size_t)s * 256 + lane * 4];
  float4 b = *(const float4*)&xr[(size_t)d * 256 + lane * 4];
  float4 w = *(const float4*)&att[lane * 4];  // (l>>4)*64+(l&15)*4 == l*4
  float ex = a.x + b.x; ex = ex > 0.f ? ex : 0.2f * ex;
  float ey = a.y + b.y; ey = ey > 0.f ? ey : 0.2f * ey;
  float ez = a.z + b.z; ez = ez > 0.f ? ez : 0.2f * ez;
  float ew = a.w + b.w; ew = ew > 0.f ? ew : 0.2f * ew;
  float p = ex * w.x + ey * w.y + ez * w.z + ew * w.w;
  p += __shfl_xor(p, 1);
  p += __shfl_xor(p, 2);
  p += __shfl_xor(p, 4);
  p += __shfl_xor(p, 8);
  if ((lane & 15) == 0) {
    int h = lane >> 4;
    score[(size_t)wid * 4 + h] = p;
    atomicMax(&mord[d * 4 + h], ford(p));
  }
}

// ---------------------------------------------------------------------------
// one wave per edge: ex = exp(score-max); atomic den += ex; acc += ex*xl[src]
// ---------------------------------------------------------------------------
__global__ __launch_bounds__(256) void edge_aggr(const float* __restrict__ xl,
                                                 const int* __restrict__ ei,
                                                 const float* __restrict__ score,
                                                 const unsigned* __restrict__ mord,
                                                 float* __restrict__ den,
                                                 float* __restrict__ acc,
                                                 int Etot, int Eorig) {
  int wid = (blockIdx.x << 2) + (threadIdx.x >> 6);
  if (wid >= Etot) return;
  int lane = threadIdx.x & 63;
  int s, d;
  if (wid < Eorig) { s = ei[wid]; d = ei[Eorig + wid]; }
  else { s = wid - Eorig; d = s; }
  int h = lane >> 4;
  float m = funord(mord[d * 4 + h]);
  float ex = __expf(score[(size_t)wid * 4 + h] - m);
  if ((lane & 15) == 0) atomicAdd(&den[d * 4 + h], ex);
  float4 a = *(const float4*)&xl[(size_t)s * 256 + lane * 4];
  float* dst = &acc[(size_t)d * 256 + lane * 4];
  atomicAdd(dst + 0, ex * a.x);
  atomicAdd(dst + 1, ex * a.y);
  atomicAdd(dst + 2, ex * a.z);
  atomicAdd(dst + 3, ex * a.w);
}

// acc[n,h,c] -> acc/den + bias (in place), concat layout [N,256]
__global__ void finalize_concat(float* __restrict__ acc, const float* __restrict__ den,
                                const float* __restrict__ bias, int N) {
  int i = blockIdx.x * blockDim.x + threadIdx.x;
  if (i >= N * 256) return;
  int n = i >> 8, c = i & 255;
  acc[i] = acc[i] / den[(n << 2) + (c >> 6)] + bias[c];
}

// column sums / sumsq over [N,256]
__global__ void bn_stats(const float* __restrict__ h, float* __restrict__ sums, int N) {
  int c = threadIdx.x;  // 256
  float s = 0.f, s2 = 0.f;
  for (int r = blockIdx.x; r < N; r += gridDim.x) {
    float v = h[(size_t)r * 256 + c];
    s += v; s2 += v * v;
  }
  atomicAdd(&sums[c], s);
  atomicAdd(&sums[256 + c], s2);
}

__global__ void bn_apply_relu(float* __restrict__ h, const float* __restrict__ sums,
                              const float* __restrict__ g, const float* __restrict__ be,
                              int N) {
  int i = blockIdx.x * blockDim.x + threadIdx.x;
  if (i >= N * 256) return;
  int c = i & 255;
  float inv_n = 1.f / (float)N;
  float mu = sums[c] * inv_n;
  float var = sums[256 + c] * inv_n - mu * mu;
  float v = (h[i] - mu) * rsqrtf(var + EPSBN);
  v = v * g[c] + be[c];
  h[i] = v > 0.f ? v : 0.f;
}

// conv2 finalize: mean over heads + bias -> o[N,64]
__global__ void finalize_mean(const float* __restrict__ acc, const float* __restrict__ den,
                              const float* __restrict__ bias, float* __restrict__ o, int N) {
  int i = blockIdx.x * blockDim.x + threadIdx.x;
  if (i >= N * 64) return;
  int n = i >> 6, c = i & 63;
  float v = 0.f;
#pragma unroll
  for (int h = 0; h < 4; ++h)
    v += acc[((size_t)n << 8) + (h << 6) + c] / den[(n << 2) + h];
  o[i] = 0.25f * v + bias[c];
}

// column stats over o[:, :32]
__global__ void bn2_stats(const float* __restrict__ o, float* __restrict__ sums, int N) {
  int c = threadIdx.x & 31;
  int rr = threadIdx.x >> 5;  // 0..7
  float s = 0.f, s2 = 0.f;
  for (int r = blockIdx.x * 8 + rr; r < N; r += gridDim.x * 8) {
    float v = o[((size_t)r << 6) + c];
    s += v; s2 += v * v;
  }
  atomicAdd(&sums[c], s);
  atomicAdd(&sums[32 + c], s2);
}

// z_mu = BN(o[:,:32]) (no affine); z_sig = sigmoid(o[:,32:])
__global__ void write_out(const float* __restrict__ o, const float* __restrict__ sums,
                          float* __restrict__ out, int N) {
  int i = blockIdx.x * blockDim.x + threadIdx.x;
  if (i >= N * 32) return;
  int n = i >> 5, c = i & 31;
  float inv_n = 1.f / (float)N;
  float mu = sums[c] * inv_n;
  float var = sums[32 + c] * inv_n - mu * mu;
  out[i] = (o[((size_t)n << 6) + c] - mu) * rsqrtf(var + EPSBN);
  float t = o[((size_t)n << 6) + 32 + c];
  out[(size_t)N * 32 + i] = 1.f / (1.f + __expf(-t));
}

extern "C" void kernel_launch(void* const* d_in, const int* in_sizes, int n_in,
                              void* d_out, int out_size, void* d_ws, size_t ws_size,
                              hipStream_t stream) {
  const float* x    = (const float*)d_in[0];
  const int*   ei   = (const int*)d_in[1];   // edge_index [2,E] int32
  const float* W1l  = (const float*)d_in[2];
  const float* W1r  = (const float*)d_in[3];
  const float* att1 = (const float*)d_in[4];
  const float* b1   = (const float*)d_in[5];
  const float* g1   = (const float*)d_in[6];
  const float* be1  = (const float*)d_in[7];
  const float* W2l  = (const float*)d_in[8];
  const float* W2r  = (const float*)d_in[9];
  const float* att2 = (const float*)d_in[10];
  const float* b2   = (const float*)d_in[11];
  float* out = (float*)d_out;

  const int N = in_sizes[0] / 256;   // 50000
  const int E = in_sizes[1] / 2;     // 800000
  const int Etot = E + N;            // + self loops

  char* ws = (char*)d_ws;
  size_t NB = (size_t)N * 256 * sizeof(float);
  float* A = (float*)ws;            ws += NB;                                // xl
  float* B = (float*)ws;            ws += NB;                                // xr
  float* C = (float*)ws;            ws += NB;                                // acc / h1 / acc2
  float* score = (float*)ws;        ws += (size_t)Etot * 4 * sizeof(float);
  unsigned* mord = (unsigned*)ws;   ws += (size_t)N * 4 * sizeof(unsigned);
  float* den = (float*)ws;          ws += (size_t)N * 4 * sizeof(float);
  float* o = (float*)ws;            ws += (size_t)N * 64 * sizeof(float);
  float* sums1 = (float*)ws;        ws += 512 * sizeof(float);
  float* sums2 = (float*)ws;        ws += 64 * sizeof(float);

  dim3 gemmGrid((N + 63) / 64, 4);
  int edgeBlocks = (Etot + 3) / 4;

  // ---- conv1 ----
  hipMemsetAsync(C, 0, NB, stream);
  hipMemsetAsync(mord, 0, (size_t)N * 4 * sizeof(unsigned), stream);
  hipMemsetAsync(den, 0, (size_t)N * 4 * sizeof(float), stream);
  hipMemsetAsync(sums1, 0, 512 * sizeof(float), stream);
  hipMemsetAsync(sums2, 0, 64 * sizeof(float), stream);

  gemm256<<<gemmGrid, 256, 0, stream>>>(x, W1l, A, N);
  gemm256<<<gemmGrid, 256, 0, stream>>>(x, W1r, B, N);
  edge_score<<<edgeBlocks, 256, 0, stream>>>(A, B, ei, att1, score, mord, Etot, E);
  edge_aggr<<<edgeBlocks, 256, 0, stream>>>(A, ei, score, mord, den, C, Etot, E);
  finalize_concat<<<(N * 256 + 255) / 256, 256, 0, stream>>>(C, den, b1, N);
  bn_stats<<<256, 256, 0, stream>>>(C, sums1, N);
  bn_apply_relu<<<(N * 256 + 255) / 256, 256, 0, stream>>>(C, sums1, g1, be1, N);

  // ---- conv2 ----
  gemm256<<<gemmGrid, 256, 0, stream>>>(C, W2l, A, N);
  gemm256<<<gemmGrid, 256, 0, stream>>>(C, W2r, B, N);
  hipMemsetAsync(C, 0, NB, stream);
  hipMemsetAsync(mord, 0, (size_t)N * 4 * sizeof(unsigned), stream);
  hipMemsetAsync(den, 0, (size_t)N * 4 * sizeof(float), stream);
  edge_score<<<edgeBlocks, 256, 0, stream>>>(A, B, ei, att2, score, mord, Etot, E);
  edge_aggr<<<edgeBlocks, 256, 0, stream>>>(A, ei, score, mord, den, C, Etot, E);
  finalize_mean<<<(N * 64 + 255) / 256, 256, 0, stream>>>(C, den, b2, o, N);
  bn2_stats<<<128, 256, 0, stream>>>(o, sums2, N);
  write_out<<<(N * 32 + 255) / 256, 256, 0, stream>>>(o, sums2, out, N);
}

// Round 3
// 1059.067 us; speedup vs baseline: 6.4845x; 6.4845x over previous
//
#include <hip/hip_runtime.h>
#include <hip/hip_bf16.h>
#include <math.h>

#define EPSBN 1e-5f

// ---------------------------------------------------------------------------
// C[M,256] = A[M,256] @ W[256,256], f32, LDS-tiled 64x64, 256 thr, 4x4/thread
// ---------------------------------------------------------------------------
__global__ __launch_bounds__(256) void gemm256(const float* __restrict__ A,
                                               const float* __restrict__ W,
                                               float* __restrict__ C, int M) {
  __shared__ float As[64][20];  // [m][k], stride 20 floats keeps float4 alignment
  __shared__ float Bs[16][68];  // [k][n], stride 68 floats
  const int tid = threadIdx.x;
  const int tx = tid & 15, ty = tid >> 4;
  const int bm = blockIdx.x * 64, bn = blockIdx.y * 64;
  float acc[4][4] = {};
  for (int k0 = 0; k0 < 256; k0 += 16) {
    {
      int r = tid >> 2;            // 0..63
      int kc = (tid & 3) * 4;      // 0,4,8,12
      int gr = bm + r;
      float4 v = make_float4(0.f, 0.f, 0.f, 0.f);
      if (gr < M) v = *(const float4*)&A[(size_t)gr * 256 + k0 + kc];
      *(float4*)&As[r][kc] = v;
      int kr = tid >> 4;           // 0..15
      int nc = (tid & 15) * 4;     // 0..60
      float4 w = *(const float4*)&W[(size_t)(k0 + kr) * 256 + bn + nc];
      *(float4*)&Bs[kr][nc] = w;
    }
    __syncthreads();
#pragma unroll
    for (int kk = 0; kk < 16; ++kk) {
      float a0 = As[ty * 4 + 0][kk];
      float a1 = As[ty * 4 + 1][kk];
      float a2 = As[ty * 4 + 2][kk];
      float a3 = As[ty * 4 + 3][kk];
      float4 b = *(float4*)&Bs[kk][tx * 4];
      acc[0][0] += a0 * b.x; acc[0][1] += a0 * b.y; acc[0][2] += a0 * b.z; acc[0][3] += a0 * b.w;
      acc[1][0] += a1 * b.x; acc[1][1] += a1 * b.y; acc[1][2] += a1 * b.z; acc[1][3] += a1 * b.w;
      acc[2][0] += a2 * b.x; acc[2][1] += a2 * b.y; acc[2][2] += a2 * b.z; acc[2][3] += a2 * b.w;
      acc[3][0] += a3 * b.x; acc[3][1] += a3 * b.y; acc[3][2] += a3 * b.z; acc[3][3] += a3 * b.w;
    }
    __syncthreads();
  }
#pragma unroll
  for (int i = 0; i < 4; ++i) {
    int gr = bm + ty * 4 + i;
    if (gr < M) {
      *(float4*)&C[(size_t)gr * 256 + bn + tx * 4] =
          make_float4(acc[i][0], acc[i][1], acc[i][2], acc[i][3]);
    }
  }
}

// ---------------------------------------------------------------------------
// CSR build: histogram by dst, single-block scan, scatter src ids
// ---------------------------------------------------------------------------
__global__ void hist_dst(const int* __restrict__ ei, int* __restrict__ cnt,
                         int Etot, int E) {
  int e = blockIdx.x * 256 + threadIdx.x;
  if (e >= Etot) return;
  int d = (e < E) ? ei[E + e] : e - E;
  atomicAdd(&cnt[d], 1);
}

__global__ __launch_bounds__(1024) void scan_block(const int* __restrict__ cnt,
                                                   int* __restrict__ rowptr,
                                                   int N, int Etot) {
  __shared__ int lds[1024];
  int t = threadIdx.x;
  int strip = (N + 1023) >> 10;
  int lo = t * strip, hi = min(lo + strip, N);
  int s = 0;
  for (int i = lo; i < hi && lo < N; ++i) s += cnt[i];
  lds[t] = s;
  __syncthreads();
  for (int off = 1; off < 1024; off <<= 1) {
    int v = (t >= off) ? lds[t - off] : 0;
    __syncthreads();
    lds[t] += v;
    __syncthreads();
  }
  int base = lds[t] - s;  // exclusive prefix of this strip
  for (int i = lo; i < hi && lo < N; ++i) { rowptr[i] = base; base += cnt[i]; }
  if (t == 1023) rowptr[N] = Etot;
}

__global__ void scatter_src(const int* __restrict__ ei, const int* __restrict__ rowptr,
                            int* __restrict__ cur, int* __restrict__ srcs,
                            int Etot, int E) {
  int e = blockIdx.x * 256 + threadIdx.x;
  if (e >= Etot) return;
  int s, d;
  if (e < E) { s = ei[e]; d = ei[E + e]; } else { s = e - E; d = s; }
  int pos = rowptr[d] + atomicAdd(&cur[d], 1);
  srcs[pos] = s;
}

// ---------------------------------------------------------------------------
// Fused GATv2 edge pass: one wave per dst node, online softmax, no atomics.
// lane l -> head h=l>>4, channels l*4..l*4+3 of the 256-wide concat.
// ---------------------------------------------------------------------------
template <int CONCAT>
__global__ __launch_bounds__(256) void gat_fused(const float* __restrict__ xl,
                                                 const float* __restrict__ xr,
                                                 const float* __restrict__ att,
                                                 const float* __restrict__ bias,
                                                 const int* __restrict__ rowptr,
                                                 const int* __restrict__ srcs,
                                                 float* __restrict__ out, int N) {
  int d = (blockIdx.x << 2) + (threadIdx.x >> 6);
  if (d >= N) return;
  int lane = threadIdx.x & 63;
  float4 xb = *(const float4*)&xr[(size_t)d * 256 + lane * 4];
  float4 w  = *(const float4*)&att[lane * 4];   // (l>>4)*64+(l&15)*4 == l*4
  int i = rowptr[d], end = rowptr[d + 1];
  float m = -3e38f, den = 0.f;
  float a0 = 0.f, a1 = 0.f, a2 = 0.f, a3 = 0.f;
  int s_next = srcs[i];
  for (; i < end; ++i) {
    int s = s_next;
    if (i + 1 < end) s_next = srcs[i + 1];
    float4 a = *(const float4*)&xl[(size_t)s * 256 + lane * 4];
    float e0 = a.x + xb.x; e0 = e0 > 0.f ? e0 : 0.2f * e0;
    float e1 = a.y + xb.y; e1 = e1 > 0.f ? e1 : 0.2f * e1;
    float e2 = a.z + xb.z; e2 = e2 > 0.f ? e2 : 0.2f * e2;
    float e3 = a.w + xb.w; e3 = e3 > 0.f ? e3 : 0.2f * e3;
    float p = e0 * w.x + e1 * w.y + e2 * w.z + e3 * w.w;
    p += __shfl_xor(p, 1);
    p += __shfl_xor(p, 2);
    p += __shfl_xor(p, 4);
    p += __shfl_xor(p, 8);   // all 16 lanes of the head group hold the score
    float nm = fmaxf(m, p);
    float corr = __expf(m - nm);
    float ex = __expf(p - nm);
    den = den * corr + ex;
    a0 = a0 * corr + ex * a.x;
    a1 = a1 * corr + ex * a.y;
    a2 = a2 * corr + ex * a.z;
    a3 = a3 * corr + ex * a.w;
    m = nm;
  }
  float inv = 1.f / den;
  if (CONCAT) {
    float4 bb = *(const float4*)&bias[lane * 4];
    *(float4*)&out[(size_t)d * 256 + lane * 4] =
        make_float4(a0 * inv + bb.x, a1 * inv + bb.y, a2 * inv + bb.z, a3 * inv + bb.w);
  } else {
    float v0 = a0 * inv, v1 = a1 * inv, v2 = a2 * inv, v3 = a3 * inv;
    v0 += __shfl_xor(v0, 16); v0 += __shfl_xor(v0, 32);
    v1 += __shfl_xor(v1, 16); v1 += __shfl_xor(v1, 32);
    v2 += __shfl_xor(v2, 16); v2 += __shfl_xor(v2, 32);
    v3 += __shfl_xor(v3, 16); v3 += __shfl_xor(v3, 32);
    if (lane < 16) {
      float4 bb = *(const float4*)&bias[lane * 4];
      *(float4*)&out[(size_t)d * 64 + lane * 4] =
          make_float4(0.25f * v0 + bb.x, 0.25f * v1 + bb.y,
                      0.25f * v2 + bb.z, 0.25f * v3 + bb.w);
    }
  }
}

// column sums / sumsq over [N,256]
__global__ void bn_stats(const float* __restrict__ h, float* __restrict__ sums, int N) {
  int c = threadIdx.x;  // 256
  float s = 0.f, s2 = 0.f;
  for (int r = blockIdx.x; r < N; r += gridDim.x) {
    float v = h[(size_t)r * 256 + c];
    s += v; s2 += v * v;
  }
  atomicAdd(&sums[c], s);
  atomicAdd(&sums[256 + c], s2);
}

__global__ void bn_apply_relu(float* __restrict__ h, const float* __restrict__ sums,
                              const float* __restrict__ g, const float* __restrict__ be,
                              int N) {
  int i = blockIdx.x * blockDim.x + threadIdx.x;
  if (i >= N * 256) return;
  int c = i & 255;
  float inv_n = 1.f / (float)N;
  float mu = sums[c] * inv_n;
  float var = sums[256 + c] * inv_n - mu * mu;
  float v = (h[i] - mu) * rsqrtf(var + EPSBN);
  v = v * g[c] + be[c];
  h[i] = v > 0.f ? v : 0.f;
}

// column stats over o[:, :32]
__global__ void bn2_stats(const float* __restrict__ o, float* __restrict__ sums, int N) {
  int c = threadIdx.x & 31;
  int rr = threadIdx.x >> 5;  // 0..7
  float s = 0.f, s2 = 0.f;
  for (int r = blockIdx.x * 8 + rr; r < N; r += gridDim.x * 8) {
    float v = o[((size_t)r << 6) + c];
    s += v; s2 += v * v;
  }
  atomicAdd(&sums[c], s);
  atomicAdd(&sums[32 + c], s2);
}

// z_mu = BN(o[:,:32]) (no affine); z_sig = sigmoid(o[:,32:])
__global__ void write_out(const float* __restrict__ o, const float* __restrict__ sums,
                          float* __restrict__ out, int N) {
  int i = blockIdx.x * blockDim.x + threadIdx.x;
  if (i >= N * 32) return;
  int n = i >> 5, c = i & 31;
  float inv_n = 1.f / (float)N;
  float mu = sums[c] * inv_n;
  float var = sums[32 + c] * inv_n - mu * mu;
  out[i] = (o[((size_t)n << 6) + c] - mu) * rsqrtf(var + EPSBN);
  float t = o[((size_t)n << 6) + 32 + c];
  out[(size_t)N * 32 + i] = 1.f / (1.f + __expf(-t));
}

extern "C" void kernel_launch(void* const* d_in, const int* in_sizes, int n_in,
                              void* d_out, int out_size, void* d_ws, size_t ws_size,
                              hipStream_t stream) {
  const float* x    = (const float*)d_in[0];
  const int*   ei   = (const int*)d_in[1];
  const float* W1l  = (const float*)d_in[2];
  const float* W1r  = (const float*)d_in[3];
  const float* att1 = (const float*)d_in[4];
  const float* b1   = (const float*)d_in[5];
  const float* g1   = (const float*)d_in[6];
  const float* be1  = (const float*)d_in[7];
  const float* W2l  = (const float*)d_in[8];
  const float* W2r  = (const float*)d_in[9];
  const float* att2 = (const float*)d_in[10];
  const float* b2   = (const float*)d_in[11];
  float* out = (float*)d_out;

  const int N = in_sizes[0] / 256;   // 50000
  const int E = in_sizes[1] / 2;     // 800000
  const int Etot = E + N;

  char* ws = (char*)d_ws;
  size_t NB = (size_t)N * 256 * sizeof(float);
  float* A = (float*)ws;       ws += NB;                              // xl
  float* B = (float*)ws;       ws += NB;                              // xr
  float* C = (float*)ws;       ws += NB;                              // h1
  float* o = (float*)ws;       ws += (size_t)N * 64 * sizeof(float);
  int* rowptr = (int*)ws;      ws += (size_t)(N + 1) * sizeof(int);
  int* cnt = (int*)ws;         ws += (size_t)N * sizeof(int);
  int* srcs = (int*)ws;        ws += (size_t)Etot * sizeof(int);
  float* sums1 = (float*)ws;   ws += 512 * sizeof(float);
  float* sums2 = (float*)ws;   ws += 64 * sizeof(float);

  dim3 gemmGrid((N + 63) / 64, 4);
  int edgeBlocks = (Etot + 255) / 256;
  int dstBlocks = (N + 3) / 4;

  // ---- CSR build (shared by both convs) ----
  hipMemsetAsync(cnt, 0, (size_t)N * sizeof(int), stream);
  hipMemsetAsync(sums1, 0, 512 * sizeof(float), stream);
  hipMemsetAsync(sums2, 0, 64 * sizeof(float), stream);
  hist_dst<<<edgeBlocks, 256, 0, stream>>>(ei, cnt, Etot, E);
  scan_block<<<1, 1024, 0, stream>>>(cnt, rowptr, N, Etot);
  hipMemsetAsync(cnt, 0, (size_t)N * sizeof(int), stream);
  scatter_src<<<edgeBlocks, 256, 0, stream>>>(ei, rowptr, cnt, srcs, Etot, E);

  // ---- conv1 ----
  gemm256<<<gemmGrid, 256, 0, stream>>>(x, W1l, A, N);
  gemm256<<<gemmGrid, 256, 0, stream>>>(x, W1r, B, N);
  gat_fused<1><<<dstBlocks, 256, 0, stream>>>(A, B, att1, b1, rowptr, srcs, C, N);
  bn_stats<<<256, 256, 0, stream>>>(C, sums1, N);
  bn_apply_relu<<<(N * 256 + 255) / 256, 256, 0, stream>>>(C, sums1, g1, be1, N);

  // ---- conv2 ----
  gemm256<<<gemmGrid, 256, 0, stream>>>(C, W2l, A, N);
  gemm256<<<gemmGrid, 256, 0, stream>>>(C, W2r, B, N);
  gat_fused<0><<<dstBlocks, 256, 0, stream>>>(A, B, att2, b2, rowptr, srcs, o, N);
  bn2_stats<<<128, 256, 0, stream>>>(o, sums2, N);
  write_out<<<(N * 32 + 255) / 256, 256, 0, stream>>>(o, sums2, out, N);
}

// Round 4
// 708.233 us; speedup vs baseline: 9.6966x; 1.4954x over previous
//
#include <hip/hip_runtime.h>
#include <math.h>

#define EPSBN 1e-5f

typedef __attribute__((ext_vector_type(8))) short short8;
typedef __attribute__((ext_vector_type(4))) float f32x4;

// RNE f32 -> bf16 (bit pattern)
__device__ __forceinline__ unsigned short f2b(float f) {
  unsigned u = __float_as_uint(f);
  return (unsigned short)((u + 0x7fffu + ((u >> 16) & 1u)) >> 16);
}
__device__ __forceinline__ float b2f(unsigned short s) {
  return __uint_as_float((unsigned)s << 16);
}
// LDS XOR swizzle (involution: XORs byte bits 4-5 with bits 7-8) -> 2 lanes/bank
__device__ __forceinline__ int swz(int b) { return b ^ (((b >> 7) & 3) << 4); }

// ---------------------------------------------------------------------------
// dual GEMM: C[M,512] = A[M,256] @ [Wl | Wr]  (bf16 in, f32 acc, bf16 out)
// Wt is pre-transposed: Wt[n][k], n in [0,512). 128x128 tile, 4 waves, BK=32.
// ---------------------------------------------------------------------------
__global__ __launch_bounds__(256) void gemm_dual(const unsigned short* __restrict__ Ab,
                                                 const unsigned short* __restrict__ Wt,
                                                 unsigned short* __restrict__ C, int M) {
  __shared__ __align__(16) short As[4096];  // 8KB [128][32] bf16, swizzled
  __shared__ __align__(16) short Bs[4096];  // 8KB [128][32] bf16 (n-major), swizzled
  const int tid = threadIdx.x;
  const int lane = tid & 63, w = tid >> 6;
  const int wr = w >> 1, wc = w & 1;
  const int bm = blockIdx.x * 128, bn = blockIdx.y * 128;

  // staging: thread covers flat bytes p0 = tid*16 and p1 = (256+tid)*16
  const int srow = tid >> 2;              // 0..63
  const int scol = (tid & 3) << 4;        // 0,16,32,48 bytes within 64B row
  const char* gA = (const char*)Ab + (size_t)(bm + srow) * 512 + scol;
  const char* gB = (const char*)Wt + (size_t)(bn + srow) * 512 + scol;
  char* wA0 = (char*)As + swz(tid * 16);
  char* wA1 = (char*)As + swz((256 + tid) * 16);
  char* wB0 = (char*)Bs + swz(tid * 16);
  char* wB1 = (char*)Bs + swz((256 + tid) * 16);

  // frag read offsets (static)
  int aoff[4], boff[4];
#pragma unroll
  for (int i = 0; i < 4; ++i) {
    aoff[i] = swz(((wr * 64 + i * 16 + (lane & 15)) << 6) + ((lane >> 4) << 4));
    boff[i] = swz(((wc * 64 + i * 16 + (lane & 15)) << 6) + ((lane >> 4) << 4));
  }

  f32x4 acc[4][4] = {};
  short8 ra0 = *(const short8*)(gA);
  short8 ra1 = *(const short8*)(gA + 64 * 512);
  short8 rb0 = *(const short8*)(gB);
  short8 rb1 = *(const short8*)(gB + 64 * 512);

  for (int ks = 0; ks < 8; ++ks) {
    *(short8*)wA0 = ra0; *(short8*)wA1 = ra1;
    *(short8*)wB0 = rb0; *(short8*)wB1 = rb1;
    __syncthreads();
    if (ks < 7) {  // prefetch next K-slice; latency hides under MFMA phase
      int off = (ks + 1) * 64;
      ra0 = *(const short8*)(gA + off);
      ra1 = *(const short8*)(gA + 64 * 512 + off);
      rb0 = *(const short8*)(gB + off);
      rb1 = *(const short8*)(gB + 64 * 512 + off);
    }
    short8 af[4], bfr[4];
#pragma unroll
    for (int i = 0; i < 4; ++i) af[i] = *(const short8*)((const char*)As + aoff[i]);
#pragma unroll
    for (int i = 0; i < 4; ++i) bfr[i] = *(const short8*)((const char*)Bs + boff[i]);
#pragma unroll
    for (int mr = 0; mr < 4; ++mr)
#pragma unroll
      for (int nc = 0; nc < 4; ++nc)
        acc[mr][nc] = __builtin_amdgcn_mfma_f32_16x16x32_bf16(af[mr], bfr[nc], acc[mr][nc], 0, 0, 0);
    __syncthreads();
  }

  // epilogue: C/D layout col=lane&15, row=(lane>>4)*4+j  (m89-verified)
#pragma unroll
  for (int mr = 0; mr < 4; ++mr) {
#pragma unroll
    for (int j = 0; j < 4; ++j) {
      int row = bm + wr * 64 + mr * 16 + (lane >> 4) * 4 + j;
      if (row < M) {
#pragma unroll
        for (int nc = 0; nc < 4; ++nc) {
          int col = bn + wc * 64 + nc * 16 + (lane & 15);
          C[(size_t)row * 512 + col] = f2b(acc[mr][nc][j]);
        }
      }
    }
  }
}

// ---------------------------------------------------------------------------
// CSR build: histogram by dst, single-block scan, scatter src ids
// ---------------------------------------------------------------------------
__global__ void hist_dst(const int* __restrict__ ei, int* __restrict__ cnt,
                         int Etot, int E) {
  int e = blockIdx.x * 256 + threadIdx.x;
  if (e >= Etot) return;
  int d = (e < E) ? ei[E + e] : e - E;
  atomicAdd(&cnt[d], 1);
}

__global__ __launch_bounds__(1024) void scan_block(const int* __restrict__ cnt,
                                                   int* __restrict__ rowptr,
                                                   int N, int Etot) {
  __shared__ int lds[1024];
  int t = threadIdx.x;
  int strip = (N + 1023) >> 10;
  int lo = t * strip, hi = min(lo + strip, N);
  int s = 0;
  for (int i = lo; i < hi && lo < N; ++i) s += cnt[i];
  lds[t] = s;
  __syncthreads();
  for (int off = 1; off < 1024; off <<= 1) {
    int v = (t >= off) ? lds[t - off] : 0;
    __syncthreads();
    lds[t] += v;
    __syncthreads();
  }
  int base = lds[t] - s;
  for (int i = lo; i < hi && lo < N; ++i) { rowptr[i] = base; base += cnt[i]; }
  if (t == 1023) rowptr[N] = Etot;
}

__global__ void scatter_src(const int* __restrict__ ei, const int* __restrict__ rowptr,
                            int* __restrict__ cur, int* __restrict__ srcs,
                            int Etot, int E) {
  int e = blockIdx.x * 256 + threadIdx.x;
  if (e >= Etot) return;
  int s, d;
  if (e < E) { s = ei[e]; d = ei[E + e]; } else { s = e - E; d = s; }
  int pos = rowptr[d] + atomicAdd(&cur[d], 1);
  srcs[pos] = s;
}

// f32 -> bf16, 4 elems/thread
__global__ void cvt_x4(const float* __restrict__ in, unsigned short* __restrict__ out, int n4) {
  int i = blockIdx.x * 256 + threadIdx.x;
  if (i >= n4) return;
  float4 v = *(const float4*)&in[(size_t)i * 4];
  ushort4 o;
  o.x = f2b(v.x); o.y = f2b(v.y); o.z = f2b(v.z); o.w = f2b(v.w);
  *(ushort4*)&out[(size_t)i * 4] = o;
}

// Wt[n][k] = (n<256 ? Wl : Wr)[k][n&255], bf16
__global__ void build_wt(const float* __restrict__ Wl, const float* __restrict__ Wr,
                         unsigned short* __restrict__ Wt) {
  int idx = blockIdx.x * 256 + threadIdx.x;  // 131072
  int n = idx >> 8, k = idx & 255;
  const float* W = (n < 256) ? Wl : Wr;
  Wt[idx] = f2b(W[k * 256 + (n & 255)]);
}

// ---------------------------------------------------------------------------
// Fused GATv2: one wave per dst, online softmax, bf16 gathers from xlr[N][512]
// (cols 0..255 = xl, 256..511 = xr). lane l -> head l>>4, channels l*4..+3.
// ---------------------------------------------------------------------------
template <int CONCAT>
__global__ __launch_bounds__(256) void gat_fused(const unsigned short* __restrict__ xlr,
                                                 const float* __restrict__ att,
                                                 const float* __restrict__ bias,
                                                 const int* __restrict__ rowptr,
                                                 const int* __restrict__ srcs,
                                                 float* __restrict__ out, int N) {
  int d = (blockIdx.x << 2) + (threadIdx.x >> 6);
  if (d >= N) return;
  int lane = threadIdx.x & 63;
  ushort4 ub = *(const ushort4*)&xlr[(size_t)d * 512 + 256 + lane * 4];
  float xbx = b2f(ub.x), xby = b2f(ub.y), xbz = b2f(ub.z), xbw = b2f(ub.w);
  float4 w = *(const float4*)&att[lane * 4];  // (l>>4)*64+(l&15)*4 == l*4
  int i = rowptr[d], end = rowptr[d + 1];
  float m = -3e38f, den = 0.f;
  float a0 = 0.f, a1 = 0.f, a2 = 0.f, a3 = 0.f;
  int s_next = srcs[i];
  for (; i < end; ++i) {
    int s = s_next;
    if (i + 1 < end) s_next = srcs[i + 1];
    ushort4 ua = *(const ushort4*)&xlr[(size_t)s * 512 + lane * 4];
    float ax = b2f(ua.x), ay = b2f(ua.y), az = b2f(ua.z), aw = b2f(ua.w);
    float e0 = ax + xbx; e0 = e0 > 0.f ? e0 : 0.2f * e0;
    float e1 = ay + xby; e1 = e1 > 0.f ? e1 : 0.2f * e1;
    float e2 = az + xbz; e2 = e2 > 0.f ? e2 : 0.2f * e2;
    float e3 = aw + xbw; e3 = e3 > 0.f ? e3 : 0.2f * e3;
    float p = e0 * w.x + e1 * w.y + e2 * w.z + e3 * w.w;
    p += __shfl_xor(p, 1);
    p += __shfl_xor(p, 2);
    p += __shfl_xor(p, 4);
    p += __shfl_xor(p, 8);
    float nm = fmaxf(m, p);
    float corr = __expf(m - nm);
    float ex = __expf(p - nm);
    den = den * corr + ex;
    a0 = a0 * corr + ex * ax;
    a1 = a1 * corr + ex * ay;
    a2 = a2 * corr + ex * az;
    a3 = a3 * corr + ex * aw;
    m = nm;
  }
  float inv = 1.f / den;
  if (CONCAT) {
    float4 bb = *(const float4*)&bias[lane * 4];
    *(float4*)&out[(size_t)d * 256 + lane * 4] =
        make_float4(a0 * inv + bb.x, a1 * inv + bb.y, a2 * inv + bb.z, a3 * inv + bb.w);
  } else {
    float v0 = a0 * inv, v1 = a1 * inv, v2 = a2 * inv, v3 = a3 * inv;
    v0 += __shfl_xor(v0, 16); v0 += __shfl_xor(v0, 32);
    v1 += __shfl_xor(v1, 16); v1 += __shfl_xor(v1, 32);
    v2 += __shfl_xor(v2, 16); v2 += __shfl_xor(v2, 32);
    v3 += __shfl_xor(v3, 16); v3 += __shfl_xor(v3, 32);
    if (lane < 16) {
      float4 bb = *(const float4*)&bias[lane * 4];
      *(float4*)&out[(size_t)d * 64 + lane * 4] =
          make_float4(0.25f * v0 + bb.x, 0.25f * v1 + bb.y,
                      0.25f * v2 + bb.z, 0.25f * v3 + bb.w);
    }
  }
}

// column sums / sumsq over [N,256] f32
__global__ void bn_stats(const float* __restrict__ h, float* __restrict__ sums, int N) {
  int c = threadIdx.x;
  float s = 0.f, s2 = 0.f;
  for (int r = blockIdx.x; r < N; r += gridDim.x) {
    float v = h[(size_t)r * 256 + c];
    s += v; s2 += v * v;
  }
  atomicAdd(&sums[c], s);
  atomicAdd(&sums[256 + c], s2);
}

// BN + ReLU, write bf16 (input to GEMM2)
__global__ void bn_apply_relu(const float* __restrict__ h, const float* __restrict__ sums,
                              const float* __restrict__ g, const float* __restrict__ be,
                              unsigned short* __restrict__ out, int N) {
  int i = blockIdx.x * 256 + threadIdx.x;  // groups of 4
  if (i >= N * 64) return;
  int base = i * 4, c = base & 255;
  float inv_n = 1.f / (float)N;
  float4 v = *(const float4*)&h[base];
  ushort4 o;
  float mu, var, t;
  mu = sums[c + 0] * inv_n; var = sums[256 + c + 0] * inv_n - mu * mu;
  t = ((v.x - mu) * rsqrtf(var + EPSBN)) * g[c + 0] + be[c + 0]; o.x = f2b(t > 0.f ? t : 0.f);
  mu = sums[c + 1] * inv_n; var = sums[256 + c + 1] * inv_n - mu * mu;
  t = ((v.y - mu) * rsqrtf(var + EPSBN)) * g[c + 1] + be[c + 1]; o.y = f2b(t > 0.f ? t : 0.f);
  mu = sums[c + 2] * inv_n; var = sums[256 + c + 2] * inv_n - mu * mu;
  t = ((v.z - mu) * rsqrtf(var + EPSBN)) * g[c + 2] + be[c + 2]; o.z = f2b(t > 0.f ? t : 0.f);
  mu = sums[c + 3] * inv_n; var = sums[256 + c + 3] * inv_n - mu * mu;
  t = ((v.w - mu) * rsqrtf(var + EPSBN)) * g[c + 3] + be[c + 3]; o.w = f2b(t > 0.f ? t : 0.f);
  *(ushort4*)&out[base] = o;
}

// column stats over o[:, :32]
__global__ void bn2_stats(const float* __restrict__ o, float* __restrict__ sums, int N) {
  int c = threadIdx.x & 31;
  int rr = threadIdx.x >> 5;
  float s = 0.f, s2 = 0.f;
  for (int r = blockIdx.x * 8 + rr; r < N; r += gridDim.x * 8) {
    float v = o[((size_t)r << 6) + c];
    s += v; s2 += v * v;
  }
  atomicAdd(&sums[c], s);
  atomicAdd(&sums[32 + c], s2);
}

__global__ void write_out(const float* __restrict__ o, const float* __restrict__ sums,
                          float* __restrict__ out, int N) {
  int i = blockIdx.x * blockDim.x + threadIdx.x;
  if (i >= N * 32) return;
  int n = i >> 5, c = i & 31;
  float inv_n = 1.f / (float)N;
  float mu = sums[c] * inv_n;
  float var = sums[32 + c] * inv_n - mu * mu;
  out[i] = (o[((size_t)n << 6) + c] - mu) * rsqrtf(var + EPSBN);
  float t = o[((size_t)n << 6) + 32 + c];
  out[(size_t)N * 32 + i] = 1.f / (1.f + __expf(-t));
}

extern "C" void kernel_launch(void* const* d_in, const int* in_sizes, int n_in,
                              void* d_out, int out_size, void* d_ws, size_t ws_size,
                              hipStream_t stream) {
  const float* x    = (const float*)d_in[0];
  const int*   ei   = (const int*)d_in[1];
  const float* W1l  = (const float*)d_in[2];
  const float* W1r  = (const float*)d_in[3];
  const float* att1 = (const float*)d_in[4];
  const float* b1   = (const float*)d_in[5];
  const float* g1   = (const float*)d_in[6];
  const float* be1  = (const float*)d_in[7];
  const float* W2l  = (const float*)d_in[8];
  const float* W2r  = (const float*)d_in[9];
  const float* att2 = (const float*)d_in[10];
  const float* b2   = (const float*)d_in[11];
  float* out = (float*)d_out;

  const int N = in_sizes[0] / 256;   // 50000
  const int E = in_sizes[1] / 2;     // 800000
  const int Etot = E + N;
  const int Npad = ((N + 127) / 128) * 128;  // 50048

  char* ws = (char*)d_ws;
  unsigned short* xb  = (unsigned short*)ws; ws += (size_t)Npad * 256 * 2;  // x bf16
  unsigned short* h1b = (unsigned short*)ws; ws += (size_t)Npad * 256 * 2;  // relu(bn(h1)) bf16
  unsigned short* AB  = (unsigned short*)ws; ws += (size_t)Npad * 512 * 2;  // [xl|xr] bf16
  unsigned short* Wt1 = (unsigned short*)ws; ws += (size_t)512 * 256 * 2;
  unsigned short* Wt2 = (unsigned short*)ws; ws += (size_t)512 * 256 * 2;
  float* C   = (float*)ws;   ws += (size_t)N * 256 * 4;                     // h1 f32
  float* o   = (float*)ws;   ws += (size_t)N * 64 * 4;
  int* rowptr = (int*)ws;    ws += (size_t)(N + 1) * 4;
  int* cnt    = (int*)ws;    ws += (size_t)N * 4;
  int* srcs   = (int*)ws;    ws += (size_t)Etot * 4;
  float* sums1 = (float*)ws; ws += 512 * 4;
  float* sums2 = (float*)ws; ws += 64 * 4;

  dim3 gemmGrid(Npad / 128, 4);
  int edgeBlocks = (Etot + 255) / 256;
  int dstBlocks = (N + 3) / 4;

  // ---- CSR build + conversions ----
  hipMemsetAsync(cnt, 0, (size_t)N * 4, stream);
  hipMemsetAsync(sums1, 0, 512 * 4, stream);
  hipMemsetAsync(sums2, 0, 64 * 4, stream);
  hist_dst<<<edgeBlocks, 256, 0, stream>>>(ei, cnt, Etot, E);
  scan_block<<<1, 1024, 0, stream>>>(cnt, rowptr, N, Etot);
  hipMemsetAsync(cnt, 0, (size_t)N * 4, stream);
  scatter_src<<<edgeBlocks, 256, 0, stream>>>(ei, rowptr, cnt, srcs, Etot, E);
  cvt_x4<<<(N * 64 + 255) / 256, 256, 0, stream>>>(x, xb, N * 64);
  build_wt<<<512, 256, 0, stream>>>(W1l, W1r, Wt1);
  build_wt<<<512, 256, 0, stream>>>(W2l, W2r, Wt2);

  // ---- conv1 ----
  gemm_dual<<<gemmGrid, 256, 0, stream>>>(xb, Wt1, AB, N);
  gat_fused<1><<<dstBlocks, 256, 0, stream>>>(AB, att1, b1, rowptr, srcs, C, N);
  bn_stats<<<256, 256, 0, stream>>>(C, sums1, N);
  bn_apply_relu<<<(N * 64 + 255) / 256, 256, 0, stream>>>(C, sums1, g1, be1, h1b, N);

  // ---- conv2 ----
  gemm_dual<<<gemmGrid, 256, 0, stream>>>(h1b, Wt2, AB, N);
  gat_fused<0><<<dstBlocks, 256, 0, stream>>>(AB, att2, b2, rowptr, srcs, o, N);
  bn2_stats<<<128, 256, 0, stream>>>(o, sums2, N);
  write_out<<<(N * 32 + 255) / 256, 256, 0, stream>>>(o, sums2, out, N);
}